// Round 1
// baseline (863.309 us; speedup 1.0000x reference)
//
#include <hip/hip_runtime.h>
#include <hip/hip_bf16.h>

#define EPSV 1e-5f

// Hardware fp32 atomic add (avoids CAS-loop lowering of atomicAdd(float*)).
__device__ inline void atomAddG(float* p, float v) { unsafeAtomicAdd(p, v); }

// ---------------- scatter layer 1: agg1[dst] += x[src], IN=3 ----------------
__global__ __launch_bounds__(256) void scatter1_kernel(
    const float* __restrict__ x, const int* __restrict__ edges,
    float* __restrict__ agg1, int E)
{
    int e = blockIdx.x * blockDim.x + threadIdx.x;
    if (e >= E) return;
    int s = edges[e];
    int d = edges[E + e];
    atomAddG(&agg1[d * 3 + 0], x[s * 3 + 0]);
    atomAddG(&agg1[d * 3 + 1], x[s * 3 + 1]);
    atomAddG(&agg1[d * 3 + 2], x[s * 3 + 2]);
}

// ------- layer 1: u1 = relu(agg1@W_rel1 + b_rel1 + x@W_root1); stats -------
__global__ __launch_bounds__(256) void layer1_kernel(
    const float* __restrict__ x, const float* __restrict__ agg1,
    const float* __restrict__ W_rel1, const float* __restrict__ b_rel1,
    const float* __restrict__ W_root1,
    float* __restrict__ u1, float* __restrict__ sums, float* __restrict__ sumsq,
    int N)
{
    const int t = threadIdx.x;
    const int f = t & 63, r4 = t >> 6;
    const float wr0 = W_rel1[f], wr1 = W_rel1[64 + f], wr2 = W_rel1[128 + f];
    const float wo0 = W_root1[f], wo1 = W_root1[64 + f], wo2 = W_root1[128 + f];
    const float bb = b_rel1[f];
    float ps = 0.f, pq = 0.f;
    const int base = blockIdx.x * 128;
    for (int i = r4; i < 128; i += 4) {
        int n = base + i;
        if (n >= N) break;
        float a0 = agg1[n * 3 + 0], a1 = agg1[n * 3 + 1], a2 = agg1[n * 3 + 2];
        float x0 = x[n * 3 + 0], x1 = x[n * 3 + 1], x2 = x[n * 3 + 2];
        float v = bb;
        v = fmaf(a0, wr0, v); v = fmaf(a1, wr1, v); v = fmaf(a2, wr2, v);
        v = fmaf(x0, wo0, v); v = fmaf(x1, wo1, v); v = fmaf(x2, wo2, v);
        v = fmaxf(v, 0.f);
        u1[n * 64 + f] = v;
        ps += v; pq += v * v;
    }
    __shared__ float lsum[4][64], lsq[4][64];
    lsum[r4][f] = ps; lsq[r4][f] = pq;
    __syncthreads();
    if (r4 == 0) {
        float s = lsum[0][f] + lsum[1][f] + lsum[2][f] + lsum[3][f];
        float q = lsq[0][f] + lsq[1][f] + lsq[2][f] + lsq[3][f];
        atomAddG(&sums[f], s);
        atomAddG(&sumsq[f], q);
    }
}

// ------------- BN: scale = g*rsqrt(var+eps), shift = b - mean*scale -------------
__global__ void bnscale_kernel(const float* __restrict__ sums, const float* __restrict__ sumsq,
                               const float* __restrict__ g, const float* __restrict__ b,
                               float invn, int C,
                               float* __restrict__ scale, float* __restrict__ shift)
{
    int f = blockIdx.x * blockDim.x + threadIdx.x;
    if (f >= C) return;
    float m = sums[f] * invn;
    float v = sumsq[f] * invn - m * m;
    float sc = g[f] * rsqrtf(v + EPSV);
    scale[f] = sc;
    shift[f] = b[f] - m * sc;
}

// -------- scatter layer 2: agg2[dst] += BN1(u1)[src], 64 feats, wave/edge --------
__global__ __launch_bounds__(256) void scatter2_kernel(
    const float* __restrict__ u1, const float* __restrict__ scale1,
    const float* __restrict__ shift1, const int* __restrict__ edges,
    float* __restrict__ agg2, int E)
{
    int t = blockIdx.x * blockDim.x + threadIdx.x;
    int e = t >> 6;
    int f = t & 63;
    if (e >= E) return;
    int s = edges[e];
    int d = edges[E + e];
    float v = fmaf(u1[s * 64 + f], scale1[f], shift1[f]);
    atomAddG(&agg2[d * 64 + f], v);
}

// -- layer 2: u2 = relu(agg2@W_rel2 + b_rel2 + BN1(u1)@W_root2), in-place on agg2 --
__global__ __launch_bounds__(256) void layer2_kernel(
    const float* __restrict__ u1, const float* __restrict__ scale1,
    const float* __restrict__ shift1,
    float* __restrict__ agg2,
    const float* __restrict__ W_rel2, const float* __restrict__ b_rel2,
    const float* __restrict__ W_root2,
    float* __restrict__ sums, float* __restrict__ sumsq, int N)
{
    __shared__ float lWrel[64 * 64];
    __shared__ float lWroot[64 * 64];
    __shared__ float lRowA[4][64];
    __shared__ float lRowH[4][64];
    __shared__ float lsum[4][64], lsq[4][64];
    const int t = threadIdx.x;
    for (int i = t; i < 4096; i += 256) {
        lWrel[i] = W_rel2[i];
        lWroot[i] = W_root2[i];
    }
    const int f = t & 63, r4 = t >> 6;
    const float bb = b_rel2[f];
    const float sc1 = scale1[f], sh1 = shift1[f];
    float ps = 0.f, pq = 0.f;
    const int base = blockIdx.x * 64;
    __syncthreads();
    for (int i = 0; i < 16; ++i) {
        int n = base + i * 4 + r4;
        bool ok = (n < N);
        if (ok) {
            lRowA[r4][f] = agg2[n * 64 + f];
            lRowH[r4][f] = fmaf(u1[n * 64 + f], sc1, sh1);
        }
        __syncthreads();
        if (ok) {
            float acc = bb;
            #pragma unroll
            for (int k = 0; k < 64; ++k) {
                acc = fmaf(lRowA[r4][k], lWrel[k * 64 + f], acc);
                acc = fmaf(lRowH[r4][k], lWroot[k * 64 + f], acc);
            }
            acc = fmaxf(acc, 0.f);
            agg2[n * 64 + f] = acc;
            ps += acc; pq += acc * acc;
        }
        __syncthreads();
    }
    lsum[r4][f] = ps; lsq[r4][f] = pq;
    __syncthreads();
    if (r4 == 0) {
        float s = lsum[0][f] + lsum[1][f] + lsum[2][f] + lsum[3][f];
        float q = lsq[0][f] + lsq[1][f] + lsq[2][f] + lsq[3][f];
        atomAddG(&sums[f], s);
        atomAddG(&sumsq[f], q);
    }
}

// ------------- pool: pooled[g] += u2 rows (raw), cnt[g] += 1, LDS-staged -------------
__global__ __launch_bounds__(256) void pool_kernel(
    const float* __restrict__ u2, const int* __restrict__ membership,
    float* __restrict__ pooled, float* __restrict__ cnt, int N)
{
    __shared__ float lsum[64 * 64];
    __shared__ float lcnt[64];
    const int t = threadIdx.x;
    for (int i = t; i < 64 * 64; i += 256) lsum[i] = 0.f;
    if (t < 64) lcnt[t] = 0.f;
    __syncthreads();
    const int f = t & 63, r4 = t >> 6;
    const int base = blockIdx.x * 1024;
    for (int i = r4; i < 1024; i += 4) {
        int n = base + i;
        if (n >= N) break;
        int g = membership[n];
        atomicAdd(&lsum[g * 64 + f], u2[n * 64 + f]);
        if (f == 0) atomicAdd(&lcnt[g], 1.0f);
    }
    __syncthreads();
    for (int i = t; i < 64 * 64; i += 256)
        if (lsum[i] != 0.f) atomAddG(&pooled[i], lsum[i]);
    if (t < 64 && lcnt[t] != 0.f) atomAddG(&cnt[t], lcnt[t]);
}

// ---- head part 1: pm = BN2(pooled/cnt); z = BN3(relu(pm@W_fc1+b_fc1)) to global ----
__global__ __launch_bounds__(256) void fc1_kernel(
    const float* __restrict__ pooled, const float* __restrict__ cnt,
    const float* __restrict__ scale2, const float* __restrict__ shift2,
    const float* __restrict__ W_fc1, const float* __restrict__ b_fc1,
    const float* __restrict__ g3, const float* __restrict__ b3,
    float* __restrict__ z)
{
    __shared__ float pm[64 * 64];
    const int t = threadIdx.x;  // column of F1 = 256
    for (int i = t; i < 4096; i += 256) {
        int g = i >> 6, f = i & 63;
        float c = fmaxf(cnt[g], 1.0f);
        pm[i] = fmaf(pooled[i] / c, scale2[f], shift2[f]);
    }
    __syncthreads();
    float s = 0.f, q = 0.f;
    const float bc = b_fc1[t];
    for (int g = 0; g < 64; ++g) {
        float acc = bc;
        #pragma unroll
        for (int k = 0; k < 64; ++k)
            acc = fmaf(pm[g * 64 + k], W_fc1[k * 256 + t], acc);
        acc = fmaxf(acc, 0.f);
        z[g * 256 + t] = acc;
        s += acc; q += acc * acc;
    }
    float m = s * (1.0f / 64.0f);
    float v = q * (1.0f / 64.0f) - m * m;
    float sc = g3[t] * rsqrtf(v + EPSV);
    float sh = b3[t] - m * sc;
    for (int g = 0; g < 64; ++g)
        z[g * 256 + t] = fmaf(z[g * 256 + t], sc, sh);
}

// ---------------- head part 2: out = z @ W_fc2 + b_fc2, (64 x 10) ----------------
__global__ __launch_bounds__(640) void fc2_kernel(
    const float* __restrict__ z, const float* __restrict__ W_fc2,
    const float* __restrict__ b_fc2, float* __restrict__ out)
{
    int t = threadIdx.x;  // 640 = 64 graphs x 10 outputs
    int g = t / 10, o = t % 10;
    float acc = b_fc2[o];
    for (int c = 0; c < 256; ++c)
        acc = fmaf(z[g * 256 + c], W_fc2[c * 10 + o], acc);
    out[g * 10 + o] = acc;
}

extern "C" void kernel_launch(void* const* d_in, const int* in_sizes, int n_in,
                              void* d_out, int out_size, void* d_ws, size_t ws_size,
                              hipStream_t stream) {
    const int N = 100000, E = 1600000;

    const float* x          = (const float*)d_in[0];
    const int*   membership = (const int*)d_in[1];
    const int*   edges      = (const int*)d_in[2];
    const float* W_rel1     = (const float*)d_in[3];
    const float* b_rel1     = (const float*)d_in[4];
    const float* W_root1    = (const float*)d_in[5];
    const float* W_rel2     = (const float*)d_in[6];
    const float* b_rel2     = (const float*)d_in[7];
    const float* W_root2    = (const float*)d_in[8];
    const float* g1         = (const float*)d_in[9];
    const float* b1         = (const float*)d_in[10];
    const float* g2         = (const float*)d_in[11];
    const float* b2         = (const float*)d_in[12];
    const float* W_fc1      = (const float*)d_in[13];
    const float* b_fc1      = (const float*)d_in[14];
    const float* g3         = (const float*)d_in[15];
    const float* b3         = (const float*)d_in[16];
    const float* W_fc2      = (const float*)d_in[17];
    const float* b_fc2      = (const float*)d_in[18];

    float* ws = (float*)d_ws;
    float* agg1   = ws;                      // 300000
    float* agg2   = agg1 + 300000;           // 6400000
    float* stats  = agg2 + 6400000;          // 512
    float* pooled = stats + 512;             // 4096
    float* cnt    = pooled + 4096;           // 64
    float* u1     = cnt + 64;                // 6400000
    float* z      = u1 + 6400000;            // 16384

    float* sums1  = stats + 0;
    float* sumsq1 = stats + 64;
    float* sums2  = stats + 128;
    float* sumsq2 = stats + 192;
    float* scale1 = stats + 256;
    float* shift1 = stats + 320;
    float* scale2 = stats + 384;
    float* shift2 = stats + 448;

    // zero agg1 | agg2 | stats | pooled | cnt in one contiguous memset
    size_t zeroFloats = 300000 + 6400000 + 512 + 4096 + 64;
    hipMemsetAsync(ws, 0, zeroFloats * sizeof(float), stream);

    // layer 1 scatter
    scatter1_kernel<<<(E + 255) / 256, 256, 0, stream>>>(x, edges, agg1, E);
    // layer 1 dense + stats
    layer1_kernel<<<(N + 127) / 128, 256, 0, stream>>>(
        x, agg1, W_rel1, b_rel1, W_root1, u1, sums1, sumsq1, N);
    // BN1 scale/shift
    bnscale_kernel<<<1, 64, 0, stream>>>(sums1, sumsq1, g1, b1, 1.0f / N, 64, scale1, shift1);
    // layer 2 scatter (BN1 applied on the fly)
    {
        long long tot = (long long)E * 64;
        int blocks = (int)((tot + 255) / 256);
        scatter2_kernel<<<blocks, 256, 0, stream>>>(u1, scale1, shift1, edges, agg2, E);
    }
    // layer 2 dense + stats (in-place on agg2)
    layer2_kernel<<<(N + 63) / 64, 256, 0, stream>>>(
        u1, scale1, shift1, agg2, W_rel2, b_rel2, W_root2, sums2, sumsq2, N);
    // BN2 scale/shift
    bnscale_kernel<<<1, 64, 0, stream>>>(sums2, sumsq2, g2, b2, 1.0f / N, 64, scale2, shift2);
    // pooling (raw u2 sums + counts)
    pool_kernel<<<(N + 1023) / 1024, 256, 0, stream>>>(agg2, membership, pooled, cnt, N);
    // head
    fc1_kernel<<<1, 256, 0, stream>>>(pooled, cnt, scale2, shift2, W_fc1, b_fc1, g3, b3, z);
    fc2_kernel<<<1, 640, 0, stream>>>(z, W_fc2, b_fc2, (float*)d_out);
}

// Round 2
// 684.444 us; speedup vs baseline: 1.2613x; 1.2613x over previous
//
#include <hip/hip_runtime.h>
#include <hip/hip_bf16.h>

#define EPSV 1e-5f

__device__ inline void atomAddG(float* p, float v) { unsafeAtomicAdd(p, v); }

// ---------------- degree histogram: deg[dst]++ ----------------
__global__ __launch_bounds__(256) void hist_kernel(
    const int* __restrict__ edges, int* __restrict__ deg, int E)
{
    int e = blockIdx.x * blockDim.x + threadIdx.x;
    if (e >= E) return;
    atomicAdd(&deg[edges[E + e]], 1);
}

// ---------------- scan pass 1: per-block exclusive scan (1024 elems/block) ----------------
__global__ __launch_bounds__(256) void scan1_kernel(
    const int* __restrict__ deg, int* __restrict__ part, int* __restrict__ bsums, int N)
{
    __shared__ int l[256];
    int t = threadIdx.x;
    int base = blockIdx.x * 1024 + t * 4;
    int v0 = 0, v1 = 0, v2 = 0, v3 = 0;
    if (base + 3 < N) {
        int4 d = *(const int4*)&deg[base];
        v0 = d.x; v1 = d.y; v2 = d.z; v3 = d.w;
    } else {
        if (base < N)     v0 = deg[base];
        if (base + 1 < N) v1 = deg[base + 1];
        if (base + 2 < N) v2 = deg[base + 2];
        if (base + 3 < N) v3 = deg[base + 3];
    }
    int tot = v0 + v1 + v2 + v3;
    l[t] = tot;
    __syncthreads();
    for (int o = 1; o < 256; o <<= 1) {
        int add = (t >= o) ? l[t - o] : 0;
        __syncthreads();
        l[t] += add;
        __syncthreads();
    }
    int incl = l[t];
    int off = incl - tot;
    if (base < N)     part[base]     = off;
    if (base + 1 < N) part[base + 1] = off + v0;
    if (base + 2 < N) part[base + 2] = off + v0 + v1;
    if (base + 3 < N) part[base + 3] = off + v0 + v1 + v2;
    if (t == 255) bsums[blockIdx.x] = incl;
}

// ---------------- scan pass 2: exclusive scan of block sums (<=128) ----------------
__global__ __launch_bounds__(128) void scan2_kernel(int* __restrict__ bsums, int nblk)
{
    __shared__ int l[128];
    int t = threadIdx.x;
    int v = (t < nblk) ? bsums[t] : 0;
    l[t] = v;
    __syncthreads();
    for (int o = 1; o < 128; o <<= 1) {
        int add = (t >= o) ? l[t - o] : 0;
        __syncthreads();
        l[t] += add;
        __syncthreads();
    }
    if (t < nblk) bsums[t] = l[t] - v;
}

// ------- scan pass 3: add block offsets; write rowstart + cursor; rowstart[N]=E -------
__global__ __launch_bounds__(256) void scan3_kernel(
    int* __restrict__ rowstart, int* __restrict__ cursor,
    const int* __restrict__ bsums, int N, int E)
{
    int i = blockIdx.x * 256 + threadIdx.x;
    if (i < N) {
        int r = rowstart[i] + bsums[i >> 10];
        rowstart[i] = r;
        cursor[i] = r;
    }
    if (i == 0) rowstart[N] = E;
}

// ---------------- counting-sort fill: srcs grouped by dst ----------------
__global__ __launch_bounds__(256) void fill_kernel(
    const int* __restrict__ edges, int* __restrict__ cursor,
    int* __restrict__ srcs, int E)
{
    int e = blockIdx.x * blockDim.x + threadIdx.x;
    if (e >= E) return;
    int s = edges[e];
    int d = edges[E + e];
    int pos = atomicAdd(&cursor[d], 1);
    srcs[pos] = s;
}

// ------- graph boundaries from sorted membership: gstart[g] for g=0..64 -------
__global__ __launch_bounds__(256) void bounds_kernel(
    const int* __restrict__ membership, int* __restrict__ gstart, int N)
{
    int n = blockIdx.x * 256 + threadIdx.x;
    if (n > N) return;
    int mp = (n == 0) ? -1 : membership[n - 1];
    int mc = (n == N) ? 64 : membership[n];
    for (int g = mp + 1; g <= mc; ++g) gstart[g] = n;
}

// ---------------- gather layer 1: agg1[n] = sum x[srcs], IN=3, thread/node ----------------
__global__ __launch_bounds__(256) void gather1_kernel(
    const float* __restrict__ x, const int* __restrict__ rowstart,
    const int* __restrict__ srcs, float* __restrict__ agg1, int N)
{
    int n = blockIdx.x * 256 + threadIdx.x;
    if (n >= N) return;
    int s0 = rowstart[n], s1 = rowstart[n + 1];
    float a0 = 0.f, a1 = 0.f, a2 = 0.f;
    for (int j = s0; j < s1; ++j) {
        int s = srcs[j];
        a0 += x[s * 3 + 0];
        a1 += x[s * 3 + 1];
        a2 += x[s * 3 + 2];
    }
    agg1[n * 3 + 0] = a0;
    agg1[n * 3 + 1] = a1;
    agg1[n * 3 + 2] = a2;
}

// ------- layer 1 dense: u1 = relu(agg1@W_rel1 + b_rel1 + x@W_root1); stats -------
__global__ __launch_bounds__(256) void layer1_kernel(
    const float* __restrict__ x, const float* __restrict__ agg1,
    const float* __restrict__ W_rel1, const float* __restrict__ b_rel1,
    const float* __restrict__ W_root1,
    float* __restrict__ u1, float* __restrict__ sums, float* __restrict__ sumsq,
    int N)
{
    const int t = threadIdx.x;
    const int f = t & 63, r4 = t >> 6;
    const float wr0 = W_rel1[f], wr1 = W_rel1[64 + f], wr2 = W_rel1[128 + f];
    const float wo0 = W_root1[f], wo1 = W_root1[64 + f], wo2 = W_root1[128 + f];
    const float bb = b_rel1[f];
    float ps = 0.f, pq = 0.f;
    const int base = blockIdx.x * 128;
    for (int i = r4; i < 128; i += 4) {
        int n = base + i;
        if (n >= N) break;
        float a0 = agg1[n * 3 + 0], a1 = agg1[n * 3 + 1], a2 = agg1[n * 3 + 2];
        float x0 = x[n * 3 + 0], x1 = x[n * 3 + 1], x2 = x[n * 3 + 2];
        float v = bb;
        v = fmaf(a0, wr0, v); v = fmaf(a1, wr1, v); v = fmaf(a2, wr2, v);
        v = fmaf(x0, wo0, v); v = fmaf(x1, wo1, v); v = fmaf(x2, wo2, v);
        v = fmaxf(v, 0.f);
        u1[n * 64 + f] = v;
        ps += v; pq += v * v;
    }
    __shared__ float lsum[4][64], lsq[4][64];
    lsum[r4][f] = ps; lsq[r4][f] = pq;
    __syncthreads();
    if (r4 == 0) {
        float s = lsum[0][f] + lsum[1][f] + lsum[2][f] + lsum[3][f];
        float q = lsq[0][f] + lsq[1][f] + lsq[2][f] + lsq[3][f];
        atomAddG(&sums[f], s);
        atomAddG(&sumsq[f], q);
    }
}

// ------------- BN: scale = g*rsqrt(var+eps), shift = b - mean*scale -------------
__global__ void bnscale_kernel(const float* __restrict__ sums, const float* __restrict__ sumsq,
                               const float* __restrict__ g, const float* __restrict__ b,
                               float invn, int C,
                               float* __restrict__ scale, float* __restrict__ shift)
{
    int f = blockIdx.x * blockDim.x + threadIdx.x;
    if (f >= C) return;
    float m = sums[f] * invn;
    float v = sumsq[f] * invn - m * m;
    float sc = g[f] * rsqrtf(v + EPSV);
    scale[f] = sc;
    shift[f] = b[f] - m * sc;
}

// ---- fused layer 2: gather(u1 rows) -> BN1 algebraic -> dense 64x64x2 -> relu
// ---- -> BN2 stats -> pooled accumulation (membership sorted). Wave per node. ----
__global__ __launch_bounds__(256) void gather2_kernel(
    const float* __restrict__ u1, const int* __restrict__ rowstart,
    const int* __restrict__ srcs,
    const float* __restrict__ scale1, const float* __restrict__ shift1,
    const int* __restrict__ membership,
    const float* __restrict__ W_rel2, const float* __restrict__ b_rel2,
    const float* __restrict__ W_root2,
    float* __restrict__ pooled, float* __restrict__ sums, float* __restrict__ sumsq,
    int N, int chunk)
{
    __shared__ float lWrel[4096];
    __shared__ float lWroot[4096];
    __shared__ float rowA[4][64];
    __shared__ float rowH[4][64];
    __shared__ float red[4][64];
    const int t = threadIdx.x;
    const int w = t >> 6, f = t & 63;
    for (int i = t; i < 4096; i += 256) {
        lWrel[i] = W_rel2[i];
        lWroot[i] = W_root2[i];
    }
    __syncthreads();
    const float sc1 = scale1[f], sh1 = shift1[f], bb = b_rel2[f];

    const int gw = blockIdx.x * 4 + w;
    const int n0 = gw * chunk;
    const int n1 = min(N, n0 + chunk);
    float ps = 0.f, pq = 0.f, pacc = 0.f;
    int curg = (n0 < n1) ? membership[n0] : -1;

    for (int n = n0; n < n1; ++n) {
        int s0 = rowstart[n], s1 = rowstart[n + 1];
        float acc = 0.f;
        int j = s0;
        for (; j + 3 < s1; j += 4) {
            int sA = srcs[j], sB = srcs[j + 1], sC = srcs[j + 2], sD = srcs[j + 3];
            float vA = u1[sA * 64 + f];
            float vB = u1[sB * 64 + f];
            float vC = u1[sC * 64 + f];
            float vD = u1[sD * 64 + f];
            acc += vA + vB + vC + vD;
        }
        for (; j < s1; ++j) acc += u1[srcs[j] * 64 + f];

        float aggv = fmaf(acc, sc1, (float)(s1 - s0) * sh1);
        float h1 = fmaf(u1[n * 64 + f], sc1, sh1);
        rowA[w][f] = aggv;
        rowH[w][f] = h1;
        __builtin_amdgcn_wave_barrier();
        float o = bb;
        #pragma unroll
        for (int k = 0; k < 64; ++k) {
            o = fmaf(rowA[w][k], lWrel[k * 64 + f], o);
            o = fmaf(rowH[w][k], lWroot[k * 64 + f], o);
        }
        __builtin_amdgcn_wave_barrier();
        o = fmaxf(o, 0.f);
        ps += o; pq += o * o;

        int g = membership[n];
        if (g != curg) {
            atomAddG(&pooled[curg * 64 + f], pacc);
            pacc = 0.f;
            curg = g;
        }
        pacc += o;
    }
    if (curg >= 0 && pacc != 0.f) atomAddG(&pooled[curg * 64 + f], pacc);
    else if (curg >= 0) atomAddG(&pooled[curg * 64 + f], pacc);

    red[w][f] = ps;
    __syncthreads();
    if (w == 0) atomAddG(&sums[f], red[0][f] + red[1][f] + red[2][f] + red[3][f]);
    __syncthreads();
    red[w][f] = pq;
    __syncthreads();
    if (w == 0) atomAddG(&sumsq[f], red[0][f] + red[1][f] + red[2][f] + red[3][f]);
}

// ---- head part 1: pm = BN2(pooled/cnt); z = BN3(relu(pm@W_fc1+b_fc1)) ----
__global__ __launch_bounds__(1024) void fc1_kernel(
    const float* __restrict__ pooled, const int* __restrict__ gstart,
    const float* __restrict__ scale2, const float* __restrict__ shift2,
    const float* __restrict__ W_fc1, const float* __restrict__ b_fc1,
    const float* __restrict__ g3, const float* __restrict__ b3,
    float* __restrict__ z)
{
    __shared__ float pm[4096];
    __shared__ float reds[4][256], redq[4][256];
    __shared__ float lsc[256], lsh[256];
    const int t = threadIdx.x;
    for (int i = t; i < 4096; i += 1024) {
        int g = i >> 6, f = i & 63;
        float c = fmaxf((float)(gstart[g + 1] - gstart[g]), 1.0f);
        pm[i] = fmaf(pooled[i] / c, scale2[f], shift2[f]);
    }
    __syncthreads();
    const int col = t & 255, grp = t >> 8;
    float acc[16];
    const float bc = b_fc1[col];
    #pragma unroll
    for (int g = 0; g < 16; ++g) acc[g] = bc;
    for (int k = 0; k < 64; ++k) {
        float wv = W_fc1[k * 256 + col];
        #pragma unroll
        for (int g = 0; g < 16; ++g)
            acc[g] = fmaf(pm[(grp * 16 + g) * 64 + k], wv, acc[g]);
    }
    float s = 0.f, q = 0.f;
    #pragma unroll
    for (int g = 0; g < 16; ++g) {
        acc[g] = fmaxf(acc[g], 0.f);
        s += acc[g]; q += acc[g] * acc[g];
    }
    reds[grp][col] = s; redq[grp][col] = q;
    __syncthreads();
    if (grp == 0) {
        float S = reds[0][col] + reds[1][col] + reds[2][col] + reds[3][col];
        float Q = redq[0][col] + redq[1][col] + redq[2][col] + redq[3][col];
        float m = S * (1.0f / 64.0f);
        float v = Q * (1.0f / 64.0f) - m * m;
        float sc = g3[col] * rsqrtf(v + EPSV);
        lsc[col] = sc;
        lsh[col] = b3[col] - m * sc;
    }
    __syncthreads();
    float sc = lsc[col], sh = lsh[col];
    #pragma unroll
    for (int g = 0; g < 16; ++g)
        z[(grp * 16 + g) * 256 + col] = fmaf(acc[g], sc, sh);
}

// ---------------- head part 2: out = z @ W_fc2 + b_fc2, (64 x 10) ----------------
__global__ __launch_bounds__(640) void fc2_kernel(
    const float* __restrict__ z, const float* __restrict__ W_fc2,
    const float* __restrict__ b_fc2, float* __restrict__ out)
{
    int t = threadIdx.x;
    int g = t / 10, o = t % 10;
    float acc = b_fc2[o];
    for (int c = 0; c < 256; ++c)
        acc = fmaf(z[g * 256 + c], W_fc2[c * 10 + o], acc);
    out[g * 10 + o] = acc;
}

extern "C" void kernel_launch(void* const* d_in, const int* in_sizes, int n_in,
                              void* d_out, int out_size, void* d_ws, size_t ws_size,
                              hipStream_t stream) {
    const int N = 100000, E = 1600000;

    const float* x          = (const float*)d_in[0];
    const int*   membership = (const int*)d_in[1];
    const int*   edges      = (const int*)d_in[2];
    const float* W_rel1     = (const float*)d_in[3];
    const float* b_rel1     = (const float*)d_in[4];
    const float* W_root1    = (const float*)d_in[5];
    const float* W_rel2     = (const float*)d_in[6];
    const float* b_rel2     = (const float*)d_in[7];
    const float* W_root2    = (const float*)d_in[8];
    const float* g1         = (const float*)d_in[9];
    const float* b1         = (const float*)d_in[10];
    const float* g2         = (const float*)d_in[11];
    const float* b2         = (const float*)d_in[12];
    const float* W_fc1      = (const float*)d_in[13];
    const float* b_fc1      = (const float*)d_in[14];
    const float* g3         = (const float*)d_in[15];
    const float* b3         = (const float*)d_in[16];
    const float* W_fc2      = (const float*)d_in[17];
    const float* b_fc2      = (const float*)d_in[18];

    // workspace layout (elements; every region multiple of 64 -> 256B aligned)
    int*   wsi      = (int*)d_ws;
    float* wsf      = (float*)d_ws;
    int*   deg      = wsi + 0;        // 100032
    float* stats    = wsf + 100032;   // 512
    float* pooled   = wsf + 100544;   // 4096
    int*   rowstart = wsi + 104640;   // 100032
    int*   cursor   = wsi + 204672;   // 100032
    int*   bsums    = wsi + 304704;   // 128
    int*   gstart   = wsi + 304832;   // 128
    int*   srcs     = wsi + 304960;   // 1600000
    float* agg1     = wsf + 1904960;  // 300032
    float* u1       = wsf + 2204992;  // 6400000
    float* z        = wsf + 8604992;  // 16384

    float* sums1  = stats + 0;
    float* sumsq1 = stats + 64;
    float* sums2  = stats + 128;
    float* sumsq2 = stats + 192;
    float* scale1 = stats + 256;
    float* shift1 = stats + 320;
    float* scale2 = stats + 384;
    float* shift2 = stats + 448;

    // zero deg | stats | pooled (contiguous prefix)
    hipMemsetAsync(d_ws, 0, (size_t)(100032 + 512 + 4096) * 4, stream);

    // CSR build
    hist_kernel<<<(E + 255) / 256, 256, 0, stream>>>(edges, deg, E);
    int nblk = (N + 1023) / 1024;  // 98
    scan1_kernel<<<nblk, 256, 0, stream>>>(deg, rowstart, bsums, N);
    scan2_kernel<<<1, 128, 0, stream>>>(bsums, nblk);
    scan3_kernel<<<(N + 255) / 256, 256, 0, stream>>>(rowstart, cursor, bsums, N, E);
    fill_kernel<<<(E + 255) / 256, 256, 0, stream>>>(edges, cursor, srcs, E);
    bounds_kernel<<<(N + 256) / 256, 256, 0, stream>>>(membership, gstart, N);

    // layer 1
    gather1_kernel<<<(N + 255) / 256, 256, 0, stream>>>(x, rowstart, srcs, agg1, N);
    layer1_kernel<<<(N + 127) / 128, 256, 0, stream>>>(
        x, agg1, W_rel1, b_rel1, W_root1, u1, sums1, sumsq1, N);
    bnscale_kernel<<<1, 64, 0, stream>>>(sums1, sumsq1, g1, b1, 1.0f / N, 64, scale1, shift1);

    // fused layer 2 + pooling
    const int GRID2 = 1024;
    int chunk = (N + GRID2 * 4 - 1) / (GRID2 * 4);  // 25
    gather2_kernel<<<GRID2, 256, 0, stream>>>(
        u1, rowstart, srcs, scale1, shift1, membership,
        W_rel2, b_rel2, W_root2, pooled, sums2, sumsq2, N, chunk);
    bnscale_kernel<<<1, 64, 0, stream>>>(sums2, sumsq2, g2, b2, 1.0f / N, 64, scale2, shift2);

    // head
    fc1_kernel<<<1, 1024, 0, stream>>>(pooled, gstart, scale2, shift2,
                                       W_fc1, b_fc1, g3, b3, z);
    fc2_kernel<<<1, 640, 0, stream>>>(z, W_fc2, b_fc2, (float*)d_out);
}

// Round 3
// 468.301 us; speedup vs baseline: 1.8435x; 1.4615x over previous
//
#include <hip/hip_runtime.h>
#include <hip/hip_bf16.h>

#define EPSV 1e-5f

__device__ inline void atomAddG(float* p, float v) { unsafeAtomicAdd(p, v); }

// ---------------- degree histogram: deg[dst]++ ----------------
__global__ __launch_bounds__(256) void hist_kernel(
    const int* __restrict__ edges, int* __restrict__ deg, int E)
{
    int e = blockIdx.x * blockDim.x + threadIdx.x;
    if (e >= E) return;
    atomicAdd(&deg[edges[E + e]], 1);
}

// ---------------- scan pass 1: per-block exclusive scan (1024 elems/block) ----------------
__global__ __launch_bounds__(256) void scan1_kernel(
    const int* __restrict__ deg, int* __restrict__ part, int* __restrict__ bsums, int N)
{
    __shared__ int l[256];
    int t = threadIdx.x;
    int base = blockIdx.x * 1024 + t * 4;
    int v0 = 0, v1 = 0, v2 = 0, v3 = 0;
    if (base + 3 < N) {
        int4 d = *(const int4*)&deg[base];
        v0 = d.x; v1 = d.y; v2 = d.z; v3 = d.w;
    } else {
        if (base < N)     v0 = deg[base];
        if (base + 1 < N) v1 = deg[base + 1];
        if (base + 2 < N) v2 = deg[base + 2];
        if (base + 3 < N) v3 = deg[base + 3];
    }
    int tot = v0 + v1 + v2 + v3;
    l[t] = tot;
    __syncthreads();
    for (int o = 1; o < 256; o <<= 1) {
        int add = (t >= o) ? l[t - o] : 0;
        __syncthreads();
        l[t] += add;
        __syncthreads();
    }
    int incl = l[t];
    int off = incl - tot;
    if (base < N)     part[base]     = off;
    if (base + 1 < N) part[base + 1] = off + v0;
    if (base + 2 < N) part[base + 2] = off + v0 + v1;
    if (base + 3 < N) part[base + 3] = off + v0 + v1 + v2;
    if (t == 255) bsums[blockIdx.x] = incl;
}

// ---------------- scan pass 2: exclusive scan of block sums (<=128) ----------------
__global__ __launch_bounds__(128) void scan2_kernel(int* __restrict__ bsums, int nblk)
{
    __shared__ int l[128];
    int t = threadIdx.x;
    int v = (t < nblk) ? bsums[t] : 0;
    l[t] = v;
    __syncthreads();
    for (int o = 1; o < 128; o <<= 1) {
        int add = (t >= o) ? l[t - o] : 0;
        __syncthreads();
        l[t] += add;
        __syncthreads();
    }
    if (t < nblk) bsums[t] = l[t] - v;
}

// ------- scan pass 3: add block offsets; write rowstart + cursor; rowstart[N]=E -------
__global__ __launch_bounds__(256) void scan3_kernel(
    int* __restrict__ rowstart, int* __restrict__ cursor,
    const int* __restrict__ bsums, int N, int E)
{
    int i = blockIdx.x * 256 + threadIdx.x;
    if (i < N) {
        int r = rowstart[i] + bsums[i >> 10];
        rowstart[i] = r;
        cursor[i] = r;
    }
    if (i == 0) rowstart[N] = E;
}

// ---------------- counting-sort fill: srcs grouped by dst ----------------
__global__ __launch_bounds__(256) void fill_kernel(
    const int* __restrict__ edges, int* __restrict__ cursor,
    int* __restrict__ srcs, int E)
{
    int e = blockIdx.x * blockDim.x + threadIdx.x;
    if (e >= E) return;
    int s = edges[e];
    int d = edges[E + e];
    int pos = atomicAdd(&cursor[d], 1);
    srcs[pos] = s;
}

// ------- graph boundaries from sorted membership: gstart[g] for g=0..64 -------
__global__ __launch_bounds__(256) void bounds_kernel(
    const int* __restrict__ membership, int* __restrict__ gstart, int N)
{
    int n = blockIdx.x * 256 + threadIdx.x;
    if (n > N) return;
    int mp = (n == 0) ? -1 : membership[n - 1];
    int mc = (n == N) ? 64 : membership[n];
    for (int g = mp + 1; g <= mc; ++g) gstart[g] = n;
}

// ---------------- gather layer 1: agg1[n] = sum x[srcs], IN=3, thread/node ----------------
__global__ __launch_bounds__(256) void gather1_kernel(
    const float* __restrict__ x, const int* __restrict__ rowstart,
    const int* __restrict__ srcs, float* __restrict__ agg1, int N)
{
    int n = blockIdx.x * 256 + threadIdx.x;
    if (n >= N) return;
    int s0 = rowstart[n], s1 = rowstart[n + 1];
    float a0 = 0.f, a1 = 0.f, a2 = 0.f;
    for (int j = s0; j < s1; ++j) {
        int s = srcs[j];
        a0 += x[s * 3 + 0];
        a1 += x[s * 3 + 1];
        a2 += x[s * 3 + 2];
    }
    agg1[n * 3 + 0] = a0;
    agg1[n * 3 + 1] = a1;
    agg1[n * 3 + 2] = a2;
}

// ------- layer 1 dense: u1 = relu(agg1@W_rel1 + b_rel1 + x@W_root1); stats -------
__global__ __launch_bounds__(256) void layer1_kernel(
    const float* __restrict__ x, const float* __restrict__ agg1,
    const float* __restrict__ W_rel1, const float* __restrict__ b_rel1,
    const float* __restrict__ W_root1,
    float* __restrict__ u1, float* __restrict__ sums, float* __restrict__ sumsq,
    int N)
{
    const int t = threadIdx.x;
    const int f = t & 63, r4 = t >> 6;
    const float wr0 = W_rel1[f], wr1 = W_rel1[64 + f], wr2 = W_rel1[128 + f];
    const float wo0 = W_root1[f], wo1 = W_root1[64 + f], wo2 = W_root1[128 + f];
    const float bb = b_rel1[f];
    float ps = 0.f, pq = 0.f;
    const int base = blockIdx.x * 128;
    for (int i = r4; i < 128; i += 4) {
        int n = base + i;
        if (n >= N) break;
        float a0 = agg1[n * 3 + 0], a1 = agg1[n * 3 + 1], a2 = agg1[n * 3 + 2];
        float x0 = x[n * 3 + 0], x1 = x[n * 3 + 1], x2 = x[n * 3 + 2];
        float v = bb;
        v = fmaf(a0, wr0, v); v = fmaf(a1, wr1, v); v = fmaf(a2, wr2, v);
        v = fmaf(x0, wo0, v); v = fmaf(x1, wo1, v); v = fmaf(x2, wo2, v);
        v = fmaxf(v, 0.f);
        u1[n * 64 + f] = v;
        ps += v; pq += v * v;
    }
    __shared__ float lsum[4][64], lsq[4][64];
    lsum[r4][f] = ps; lsq[r4][f] = pq;
    __syncthreads();
    if (r4 == 0) {
        float s = lsum[0][f] + lsum[1][f] + lsum[2][f] + lsum[3][f];
        float q = lsq[0][f] + lsq[1][f] + lsq[2][f] + lsq[3][f];
        atomAddG(&sums[f], s);
        atomAddG(&sumsq[f], q);
    }
}

// ------------- BN: scale = g*rsqrt(var+eps), shift = b - mean*scale -------------
__global__ void bnscale_kernel(const float* __restrict__ sums, const float* __restrict__ sumsq,
                               const float* __restrict__ g, const float* __restrict__ b,
                               float invn, int C,
                               float* __restrict__ scale, float* __restrict__ shift)
{
    int f = blockIdx.x * blockDim.x + threadIdx.x;
    if (f >= C) return;
    float m = sums[f] * invn;
    float v = sumsq[f] * invn - m * m;
    float sc = g[f] * rsqrtf(v + EPSV);
    scale[f] = sc;
    shift[f] = b[f] - m * sc;
}

// ---- transform: h1 = BN1(u1); t[n] = h1@W_rel2 (IN-PLACE over u1);
// ----            p[n] = h1@W_root2 + b_rel2. Dense, LDS-staged rows. ----
__global__ __launch_bounds__(256) void transform_kernel(
    float* __restrict__ u1t,                 // read u1, write t in-place
    float* __restrict__ p,
    const float* __restrict__ scale1, const float* __restrict__ shift1,
    const float* __restrict__ W_rel2, const float* __restrict__ b_rel2,
    const float* __restrict__ W_root2, int N)
{
    __shared__ float lWrel[4096];
    __shared__ float lWroot[4096];
    __shared__ float rowH[4][64];
    const int t = threadIdx.x;
    const int f = t & 63, r4 = t >> 6;
    for (int i = t; i < 4096; i += 256) {
        lWrel[i] = W_rel2[i];
        lWroot[i] = W_root2[i];
    }
    __syncthreads();
    const float sc1 = scale1[f], sh1 = shift1[f], bb = b_rel2[f];
    const int base = blockIdx.x * 64;
    for (int i = 0; i < 16; ++i) {
        int n = base + i * 4 + r4;
        bool ok = (n < N);
        if (ok) rowH[r4][f] = fmaf(u1t[n * 64 + f], sc1, sh1);
        __syncthreads();
        if (ok) {
            float o1 = 0.f, o2 = bb;
            #pragma unroll
            for (int k = 0; k < 64; ++k) {
                float h = rowH[r4][k];
                o1 = fmaf(h, lWrel[k * 64 + f], o1);
                o2 = fmaf(h, lWroot[k * 64 + f], o2);
            }
            u1t[n * 64 + f] = o1;
            p[n * 64 + f] = o2;
        }
        __syncthreads();
    }
}

// ---- gather+pool: u2[n] = relu(sum_src t[src] + p[n]); BN2 stats; pooled sums.
// ---- Wave per node-chunk, lane = feature, 8-deep load pipeline, no big LDS. ----
__global__ __launch_bounds__(256, 8) void gatherpool_kernel(
    const float* __restrict__ t, const float* __restrict__ p,
    const int* __restrict__ rowstart, const int* __restrict__ srcs,
    const int* __restrict__ membership,
    float* __restrict__ pooled, float* __restrict__ sums, float* __restrict__ sumsq,
    int N, int chunk)
{
    __shared__ float red[4][64];
    const int tid = threadIdx.x;
    const int w = tid >> 6, f = tid & 63;
    const int gw = __builtin_amdgcn_readfirstlane(blockIdx.x * 4 + w);
    const int n0 = gw * chunk;
    const int n1 = min(N, n0 + chunk);
    float ps = 0.f, pq = 0.f, pacc = 0.f;
    int curg = (n0 < N) ? membership[n0] : -1;

    for (int n = n0; n < n1; ++n) {
        int s0 = rowstart[n], s1 = rowstart[n + 1];
        float acc = p[n * 64 + f];
        int j = s0;
        for (; j + 7 < s1; j += 8) {
            int i0 = srcs[j] * 64 + f, i1 = srcs[j + 1] * 64 + f;
            int i2 = srcs[j + 2] * 64 + f, i3 = srcs[j + 3] * 64 + f;
            int i4 = srcs[j + 4] * 64 + f, i5 = srcs[j + 5] * 64 + f;
            int i6 = srcs[j + 6] * 64 + f, i7 = srcs[j + 7] * 64 + f;
            float v0 = t[i0], v1 = t[i1], v2 = t[i2], v3 = t[i3];
            float v4 = t[i4], v5 = t[i5], v6 = t[i6], v7 = t[i7];
            acc += ((v0 + v1) + (v2 + v3)) + ((v4 + v5) + (v6 + v7));
        }
        for (; j < s1; ++j) acc += t[srcs[j] * 64 + f];

        acc = fmaxf(acc, 0.f);
        ps += acc; pq += acc * acc;

        int g = membership[n];
        if (g != curg) {
            atomAddG(&pooled[curg * 64 + f], pacc);
            pacc = 0.f;
            curg = g;
        }
        pacc += acc;
    }
    if (curg >= 0) atomAddG(&pooled[curg * 64 + f], pacc);

    red[w][f] = ps;
    __syncthreads();
    if (w == 0) atomAddG(&sums[f], red[0][f] + red[1][f] + red[2][f] + red[3][f]);
    __syncthreads();
    red[w][f] = pq;
    __syncthreads();
    if (w == 0) atomAddG(&sumsq[f], red[0][f] + red[1][f] + red[2][f] + red[3][f]);
}

// ---- head part 1: pm = BN2(pooled/cnt); z = BN3(relu(pm@W_fc1+b_fc1)) ----
__global__ __launch_bounds__(1024) void fc1_kernel(
    const float* __restrict__ pooled, const int* __restrict__ gstart,
    const float* __restrict__ scale2, const float* __restrict__ shift2,
    const float* __restrict__ W_fc1, const float* __restrict__ b_fc1,
    const float* __restrict__ g3, const float* __restrict__ b3,
    float* __restrict__ z)
{
    __shared__ float pm[4096];
    __shared__ float reds[4][256], redq[4][256];
    __shared__ float lsc[256], lsh[256];
    const int t = threadIdx.x;
    for (int i = t; i < 4096; i += 1024) {
        int g = i >> 6, f = i & 63;
        float c = fmaxf((float)(gstart[g + 1] - gstart[g]), 1.0f);
        pm[i] = fmaf(pooled[i] / c, scale2[f], shift2[f]);
    }
    __syncthreads();
    const int col = t & 255, grp = t >> 8;
    float acc[16];
    const float bc = b_fc1[col];
    #pragma unroll
    for (int g = 0; g < 16; ++g) acc[g] = bc;
    for (int k = 0; k < 64; ++k) {
        float wv = W_fc1[k * 256 + col];
        #pragma unroll
        for (int g = 0; g < 16; ++g)
            acc[g] = fmaf(pm[(grp * 16 + g) * 64 + k], wv, acc[g]);
    }
    float s = 0.f, q = 0.f;
    #pragma unroll
    for (int g = 0; g < 16; ++g) {
        acc[g] = fmaxf(acc[g], 0.f);
        s += acc[g]; q += acc[g] * acc[g];
    }
    reds[grp][col] = s; redq[grp][col] = q;
    __syncthreads();
    if (grp == 0) {
        float S = reds[0][col] + reds[1][col] + reds[2][col] + reds[3][col];
        float Q = redq[0][col] + redq[1][col] + redq[2][col] + redq[3][col];
        float m = S * (1.0f / 64.0f);
        float v = Q * (1.0f / 64.0f) - m * m;
        float sc = g3[col] * rsqrtf(v + EPSV);
        lsc[col] = sc;
        lsh[col] = b3[col] - m * sc;
    }
    __syncthreads();
    float sc = lsc[col], sh = lsh[col];
    #pragma unroll
    for (int g = 0; g < 16; ++g)
        z[(grp * 16 + g) * 256 + col] = fmaf(acc[g], sc, sh);
}

// ---------------- head part 2: out = z @ W_fc2 + b_fc2, (64 x 10) ----------------
__global__ __launch_bounds__(640) void fc2_kernel(
    const float* __restrict__ z, const float* __restrict__ W_fc2,
    const float* __restrict__ b_fc2, float* __restrict__ out)
{
    int t = threadIdx.x;
    int g = t / 10, o = t % 10;
    float acc = b_fc2[o];
    for (int c = 0; c < 256; ++c)
        acc = fmaf(z[g * 256 + c], W_fc2[c * 10 + o], acc);
    out[g * 10 + o] = acc;
}

extern "C" void kernel_launch(void* const* d_in, const int* in_sizes, int n_in,
                              void* d_out, int out_size, void* d_ws, size_t ws_size,
                              hipStream_t stream) {
    const int N = 100000, E = 1600000;

    const float* x          = (const float*)d_in[0];
    const int*   membership = (const int*)d_in[1];
    const int*   edges      = (const int*)d_in[2];
    const float* W_rel1     = (const float*)d_in[3];
    const float* b_rel1     = (const float*)d_in[4];
    const float* W_root1    = (const float*)d_in[5];
    const float* W_rel2     = (const float*)d_in[6];
    const float* b_rel2     = (const float*)d_in[7];
    const float* W_root2    = (const float*)d_in[8];
    const float* g1         = (const float*)d_in[9];
    const float* b1         = (const float*)d_in[10];
    const float* g2         = (const float*)d_in[11];
    const float* b2         = (const float*)d_in[12];
    const float* W_fc1      = (const float*)d_in[13];
    const float* b_fc1      = (const float*)d_in[14];
    const float* g3         = (const float*)d_in[15];
    const float* b3         = (const float*)d_in[16];
    const float* W_fc2      = (const float*)d_in[17];
    const float* b_fc2      = (const float*)d_in[18];

    // workspace layout (elements; regions 256B-aligned)
    int*   wsi      = (int*)d_ws;
    float* wsf      = (float*)d_ws;
    int*   deg      = wsi + 0;        // 100032
    float* stats    = wsf + 100032;   // 512
    float* pooled   = wsf + 100544;   // 4096
    int*   rowstart = wsi + 104640;   // 100032
    int*   cursor   = wsi + 204672;   // 100032
    int*   bsums    = wsi + 304704;   // 128
    int*   gstart   = wsi + 304832;   // 128
    int*   srcs     = wsi + 304960;   // 1600000
    float* agg1     = wsf + 1904960;  // 300032
    float* u1       = wsf + 2204992;  // 6400000 (becomes t in-place)
    float* z        = wsf + 8604992;  // 16384
    float* pbuf     = wsf + 8621376;  // 6400000

    float* sums1  = stats + 0;
    float* sumsq1 = stats + 64;
    float* sums2  = stats + 128;
    float* sumsq2 = stats + 192;
    float* scale1 = stats + 256;
    float* shift1 = stats + 320;
    float* scale2 = stats + 384;
    float* shift2 = stats + 448;

    // zero deg | stats | pooled (contiguous prefix)
    hipMemsetAsync(d_ws, 0, (size_t)(100032 + 512 + 4096) * 4, stream);

    // CSR build
    hist_kernel<<<(E + 255) / 256, 256, 0, stream>>>(edges, deg, E);
    int nblk = (N + 1023) / 1024;  // 98
    scan1_kernel<<<nblk, 256, 0, stream>>>(deg, rowstart, bsums, N);
    scan2_kernel<<<1, 128, 0, stream>>>(bsums, nblk);
    scan3_kernel<<<(N + 255) / 256, 256, 0, stream>>>(rowstart, cursor, bsums, N, E);
    fill_kernel<<<(E + 255) / 256, 256, 0, stream>>>(edges, cursor, srcs, E);
    bounds_kernel<<<(N + 256) / 256, 256, 0, stream>>>(membership, gstart, N);

    // layer 1
    gather1_kernel<<<(N + 255) / 256, 256, 0, stream>>>(x, rowstart, srcs, agg1, N);
    layer1_kernel<<<(N + 127) / 128, 256, 0, stream>>>(
        x, agg1, W_rel1, b_rel1, W_root1, u1, sums1, sumsq1, N);
    bnscale_kernel<<<1, 64, 0, stream>>>(sums1, sumsq1, g1, b1, 1.0f / N, 64, scale1, shift1);

    // layer 2: dense transform (t in-place over u1, p separate) then streaming gather
    transform_kernel<<<(N + 63) / 64, 256, 0, stream>>>(
        u1, pbuf, scale1, shift1, W_rel2, b_rel2, W_root2, N);
    {
        const int GRID2 = 2048;  // 8 blocks/CU target
        int chunk = (N + GRID2 * 4 - 1) / (GRID2 * 4);  // 13
        gatherpool_kernel<<<GRID2, 256, 0, stream>>>(
            u1, pbuf, rowstart, srcs, membership, pooled, sums2, sumsq2, N, chunk);
    }
    bnscale_kernel<<<1, 64, 0, stream>>>(sums2, sumsq2, g2, b2, 1.0f / N, 64, scale2, shift2);

    // head
    fc1_kernel<<<1, 1024, 0, stream>>>(pooled, gstart, scale2, shift2,
                                       W_fc1, b_fc1, g3, b3, z);
    fc2_kernel<<<1, 640, 0, stream>>>(z, W_fc2, b_fc2, (float*)d_out);
}